// Round 8
// baseline (21.762 us; speedup 1.0000x reference)
//
#include <hip/hip_runtime.h>
#include <math.h>

constexpr int kB = 2, kP = 300, kF = 512, kH = 128, kW = 128, kTH = 512, kTW = 512;
constexpr float kDelta = 7000.0f;
constexpr float kCut = 0.0363f;   // skip p < ~1e-4 contributions (improb err <= ~1e-3)
constexpr float kThr2 = 0.012928f;// (kCut + 0.0774 pixel-center tile radius)^2
constexpr float kLogInside = -15.9423847f; // log1p(-(1-1e-7f)) = ln(2^-23)
constexpr int kS4 = 3072;         // float4s per batch in ws: A[512] B[512] C[512] V[1024] U[512]

// ---------------- K1: per-batch face prep (2 blocks x 512) ----------------
// Compacted front-face k is DEALT to slot (k&7)*64 + (k>>3). Bijection on [0,512):
// slots for k<n written by front threads, slots for j>=n prefilled by thread j.
__global__ __launch_bounds__(512) void prep(const float* __restrict__ pts,
                                            const int* __restrict__ faces,
                                            const float* __restrict__ uvs,
                                            float4* __restrict__ ws4) {
    int b = (int)blockIdx.x;
    int tid = (int)threadIdx.x, lane = tid & 63, wv = tid >> 6;
    __shared__ int s_wsum[8];

    int f = tid;
    int i0 = faces[f * 3 + 0], i1 = faces[f * 3 + 1], i2 = faces[f * 3 + 2];
    const float* pb = pts + b * kP * 3;
    float x0 = pb[i0 * 3], y0 = pb[i0 * 3 + 1], z0 = pb[i0 * 3 + 2];
    float x1 = pb[i1 * 3], y1 = pb[i1 * 3 + 1], z1 = pb[i1 * 3 + 2];
    float x2 = pb[i2 * 3], y2 = pb[i2 * 3 + 1], z2 = pb[i2 * 3 + 2];
    float area = (x1 - x0) * (y2 - y0) - (y1 - y0) * (x2 - x0);
    bool front = area > 1e-8f;

    unsigned long long bal = __ballot(front);
    if (lane == 0) s_wsum[wv] = __popcll(bal);
    __syncthreads();
    int n = 0, base = 0;
#pragma unroll
    for (int w = 0; w < 8; ++w) { n += s_wsum[w]; base += (w < wv) ? s_wsum[w] : 0; }
    int k = base + __popcll(bal & ((1ull << lane) - 1ull));  // compacted index

    float4* A = ws4 + (size_t)b * kS4;
    float4* B = A + 512;
    float4* C = B + 512;
    float4* V = C + 512;
    float4* U = V + 1024;

    if (tid >= n) {  // prefill empty slot(tid): never inside, never admitted, NaN-free
        int s = ((tid & 7) << 6) | (tid >> 3);
        A[s] = make_float4(0.0f, 0.0f, -1e30f, 0.0f);
        B[s] = make_float4(0.0f, -1e30f, 0.0f, 0.0f);
        C[s] = make_float4(-1e30f, 0.0f, 0.0f, 0.0f);
        V[s * 2 + 0] = make_float4(1e15f, 1e15f, 1e15f, 1e15f);
        V[s * 2 + 1] = make_float4(1e15f, 1e15f, 0.0f, 0.0f);
        U[s] = make_float4(0.0f, 0.0f, 0.0f, 0.0f);
    }
    if (front) {
        int s = ((k & 7) << 6) | (k >> 3);  // deal across waves
        float inv_a = 1.0f / area;
        float e0x = x2 - x1, e0y = y2 - y1;
        float e1x = x0 - x2, e1y = y0 - y2;
        float e2x = x1 - x0, e2y = y1 - y0;
        float l0 = fmaf(e0x, e0x, e0y * e0y);
        float l1 = fmaf(e1x, e1x, e1y * e1y);
        float l2 = fmaf(e2x, e2x, e2y * e2y);
        float s0 = rsqrtf(l0 + 1e-12f);  // unit-normal scale: 1/len_i
        float s1 = rsqrtf(l1 + 1e-12f);
        float s2 = rsqrtf(l2 + 1e-12f);
        // L_i(p) = A_i px + B_i py + C_i = signed distance to edge-line i
        float A0 = -e0y * s0, B0 = e0x * s0, C0 = (e0y * x1 - e0x * y1) * s0;
        float A1 = -e1y * s1, B1 = e1x * s1, C1 = (e1y * x2 - e1x * y2) * s1;
        float A2 = -e2y * s2, B2 = e2x * s2, C2 = (e2y * x0 - e2x * y0) * s2;
        float a0 = -e0y * inv_a, b0 = e0x * inv_a, c0 = (e0y * x1 - e0x * y1) * inv_a;
        float a1 = -e1y * inv_a, b1 = e1x * inv_a, c1 = (e1y * x2 - e1x * y2) * inv_a;
        float a2 = -e2y * inv_a, b2 = e2x * inv_a, c2 = (e2y * x0 - e2x * y0) * inv_a;
        A[s] = make_float4(A0, B0, C0, A1);
        B[s] = make_float4(B1, C1, A2, B2);
        C[s] = make_float4(C2,
                           a0 * z0 + a1 * z1 + a2 * z2,
                           b0 * z0 + b1 * z1 + b2 * z2,
                           c0 * z0 + c1 * z1 + c2 * z2);
        const float* ub = uvs + b * kP * 2;
        V[s * 2 + 0] = make_float4(x0, y0, x1, y1);
        V[s * 2 + 1] = make_float4(x2, y2, ub[i0 * 2], ub[i0 * 2 + 1]);
        U[s] = make_float4(ub[i1 * 2], ub[i1 * 2 + 1], ub[i2 * 2], ub[i2 * 2 + 1]);
    }
}

// ---------------- K2: render (512 blocks x 512) ----------------
__global__ __launch_bounds__(512, 6) void render(const float4* __restrict__ ws4,
                                                 const float* __restrict__ tex,
                                                 float* __restrict__ out) {
    __shared__ float4 s_all[kS4];  // 48 KB: A|B|C|V|U  (A-C region reused for reduce)
    float4* sA = s_all;
    float4* sB = s_all + 512;
    float4* sC = s_all + 1024;
    float4* sV = s_all + 1536;
    float4* sU = s_all + 2560;
    float* s_bz = (float*)s_all;                    // post-loop aliases (sA dead)
    int* s_bi = (int*)((char*)s_all + 2048);
    float* s_lm = (float*)((char*)s_all + 4096);

    int tile = (int)blockIdx.x;
    int b = tile >> 8;
    int rem = tile & 255;
    int ty = rem >> 4, tx = rem & 15;
    int tid = (int)threadIdx.x;
    int lane = tid & 63;
    int wv = tid >> 6;

    // stage records: linear coalesced 48 KB copy from ws (L2-resident)
    {
        const float4* src = ws4 + (size_t)b * kS4;
        for (int i = tid; i < kS4; i += 512) s_all[i] = src[i];
    }
    __syncthreads();

    int pyi = ty * 8 + (lane >> 3);
    int pxi = tx * 8 + (lane & 7);
    float px = ((float)pxi + 0.5f) * (2.0f / 128.0f) - 1.0f;
    float py = 1.0f - ((float)pyi + 0.5f) * (2.0f / 128.0f);

    // cull: thread tid tests slot tid (exact dist-to-triangle at tile center)
    float cx = (float)(tx * 8 + 4) * (2.0f / 128.0f) - 1.0f;
    float cy = 1.0f - (float)(ty * 8 + 4) * (2.0f / 128.0f);
    unsigned long long m;
    {
        int slt = tid;
        float4 a4 = sA[slt];
        float4 b4 = sB[slt];
        float4 c4 = sC[slt];
        float L0 = fmaf(a4.x, cx, fmaf(a4.y, cy, a4.z));
        float L1 = fmaf(a4.w, cx, fmaf(b4.x, cy, b4.y));
        float L2 = fmaf(b4.z, cx, fmaf(b4.w, cy, c4.x));
        float minc = fminf(fminf(L0, L1), L2);
        float4 vA = sV[slt * 2 + 0];
        float4 vB = sV[slt * 2 + 1];
        float e0x = vB.x - vA.z, e0y = vB.y - vA.w;
        float e1x = vA.x - vB.x, e1y = vA.y - vB.y;
        float e2x = vA.z - vA.x, e2y = vA.w - vA.y;
        float p0x = cx - vA.x, p0y = cy - vA.y;
        float p1x = cx - vA.z, p1y = cy - vA.w;
        float p2x = cx - vB.x, p2y = cy - vB.y;
        float dot0 = fmaf(p1x, e0x, p1y * e0y), len0 = fmaf(e0x, e0x, e0y * e0y);
        float dot1 = fmaf(p2x, e1x, p2y * e1y), len1 = fmaf(e1x, e1x, e1y * e1y);
        float dot2 = fmaf(p0x, e2x, p0y * e2y), len2 = fmaf(e2x, e2x, e2y * e2y);
        float c0 = (dot0 >= 0.0f && dot0 <= len0) ? L0 * L0 : 1e30f;
        float c1 = (dot1 >= 0.0f && dot1 <= len1) ? L1 * L1 : 1e30f;
        float c2 = (dot2 >= 0.0f && dot2 <= len2) ? L2 * L2 : 1e30f;
        float dv0 = fmaf(p0x, p0x, p0y * p0y);
        float dv1 = fmaf(p1x, p1x, p1y * p1y);
        float dv2 = fmaf(p2x, p2x, p2y * p2y);
        float d2c = fminf(fminf(fminf(c0, c1), fminf(c2, dv0)), fminf(dv1, dv2));
        bool admit = (minc >= 0.0f) | (d2c <= kThr2);
        m = __ballot(admit);
    }

    float bestz = -1e9f;
    int besti = -1, icnt = 0;  // besti holds compacted index k (global face order)
    float lm = 0.0f;

    while (m) {
        int l = (int)__builtin_ctzll(m);
        m &= (m - 1);
        int fs = (wv << 6) + l;  // LDS slot (wave-uniform)
        int k = (l << 3) | wv;   // compacted face index, ascending in l
        float4 h0 = sA[fs];
        float4 h1 = sB[fs];
        float4 h2 = sC[fs];
        float L0 = fmaf(h0.x, px, fmaf(h0.y, py, h0.z));
        float L1 = fmaf(h0.w, px, fmaf(h1.x, py, h1.y));
        float L2 = fmaf(h1.z, px, fmaf(h1.w, py, h2.x));
        float minL = fminf(fminf(L0, L1), L2);
        bool inside = minL >= 0.0f;
        float z = fmaf(h2.y, px, fmaf(h2.z, py, h2.w));
        if (inside && z > bestz) { bestz = z; besti = k; }
        icnt += inside ? 1 : 0;
        float db = fminf(fminf(fabsf(L0), fabsf(L1)), fabsf(L2));  // lower bound on d
        bool need = (!inside) & (db < kCut);
        if (__any(need)) {
            float4 vA = sV[fs * 2 + 0];
            float4 vB = sV[fs * 2 + 1];
            float e0x = vB.x - vA.z, e0y = vB.y - vA.w;
            float e1x = vA.x - vB.x, e1y = vA.y - vB.y;
            float e2x = vA.z - vA.x, e2y = vA.w - vA.y;
            float p0x = px - vA.x, p0y = py - vA.y;
            float p1x = px - vA.z, p1y = py - vA.w;
            float p2x = px - vB.x, p2y = py - vB.y;
            float dot0 = fmaf(p1x, e0x, p1y * e0y), len0 = fmaf(e0x, e0x, e0y * e0y);
            float dot1 = fmaf(p2x, e1x, p2y * e1y), len1 = fmaf(e1x, e1x, e1y * e1y);
            float dot2 = fmaf(p0x, e2x, p0y * e2y), len2 = fmaf(e2x, e2x, e2y * e2y);
            float c0 = (dot0 >= 0.0f && dot0 <= len0) ? L0 * L0 : 1e30f;
            float c1 = (dot1 >= 0.0f && dot1 <= len1) ? L1 * L1 : 1e30f;
            float c2 = (dot2 >= 0.0f && dot2 <= len2) ? L2 * L2 : 1e30f;
            float dv0 = fmaf(p0x, p0x, p0y * p0y);
            float dv1 = fmaf(p1x, p1x, p1y * p1y);
            float dv2 = fmaf(p2x, p2x, p2y * p2y);
            float d2 = fminf(fminf(fminf(c0, c1), fminf(c2, dv0)), fminf(dv1, dv2));
            float p = __expf(-kDelta * d2);
            p = fminf(p, 1.0f - 1e-7f);
            float lp = __logf(1.0f - p);  // == log1p(-p): accurate over admitted range
            lm += need ? lp : 0.0f;
        }
    }
    lm = fmaf((float)icnt, kLogInside, lm);

    __syncthreads();  // all waves done READING sA region before aliasing it
    s_bz[tid] = bestz;
    s_bi[tid] = besti;
    s_lm[tid] = lm;
    __syncthreads();

    if (tid < 64) {
        float bz = s_bz[tid];
        int bi = s_bi[tid];
        float L = s_lm[tid];
#pragma unroll
        for (int w = 1; w < 8; ++w) {
            float z2 = s_bz[w * 64 + tid];
            int ii = s_bi[w * 64 + tid];
            L += s_lm[w * 64 + tid];
            // first-max: lowest compacted index (== earliest original face) wins ties
            if (z2 > bz || (z2 == bz && ii >= 0 && (unsigned)ii < (unsigned)bi)) {
                bz = z2; bi = ii;
            }
        }
        float improb = 1.0f - expf(L);
        float u = 0.0f, v = 0.0f, mk = 0.0f;
        if (bi >= 0) {
            int slot = ((bi & 7) << 6) | (bi >> 3);
            float4 vA = sV[slot * 2 + 0];
            float4 vB = sV[slot * 2 + 1];
            float x0 = vA.x, y0 = vA.y, x1 = vA.z, y1 = vA.w, x2 = vB.x, y2 = vB.y;
            float area = (x1 - x0) * (y2 - y0) - (y1 - y0) * (x2 - x0);
            float inv_a = 1.0f / area;
            // exact reference formulation
            float w0 = ((x2 - x1) * (py - y1) - (y2 - y1) * (px - x1)) * inv_a;
            float w1 = ((x0 - x2) * (py - y2) - (y0 - y2) * (px - x2)) * inv_a;
            float w2 = ((x1 - x0) * (py - y0) - (y1 - y0) * (px - x0)) * inv_a;
            float4 uq = sU[slot];
            u = w0 * vB.z + w1 * uq.x + w2 * uq.z;
            v = w0 * vB.w + w1 * uq.y + w2 * uq.w;
            mk = w0 + w1 + w2;
        }
        float uc = fminf(fmaxf(u, 0.0f), 1.0f);
        float vc = fminf(fmaxf(v, 0.0f), 1.0f);
        float fx = uc * (float)(kTW - 1);
        float fy = (1.0f - vc) * (float)(kTH - 1);
        int xi0 = (int)floorf(fx), yi0 = (int)floorf(fy);
        int xi1 = min(xi0 + 1, kTW - 1), yi1 = min(yi0 + 1, kTH - 1);
        float wx = fx - (float)xi0, wy = fy - (float)yi0;
        float w00 = (1.0f - wx) * (1.0f - wy);
        float w01 = wx * (1.0f - wy);
        float w10 = (1.0f - wx) * wy;
        float w11 = wx * wy;
        int o00 = yi0 * kTW + xi0, o01 = yi0 * kTW + xi1;
        int o10 = yi1 * kTW + xi0, o11 = yi1 * kTW + xi1;
        const float* tb = tex + (size_t)b * 3 * kTH * kTW;
        float cols[3];
#pragma unroll
        for (int c = 0; c < 3; ++c) {
            const float* tc = tb + c * kTH * kTW;
            cols[c] = (tc[o00] * w00 + tc[o01] * w01 + tc[o10] * w10 + tc[o11] * w11) * mk;
        }
        int pix = (b * kH + pyi) * kW + pxi;
        out[pix * 3 + 0] = cols[0];
        out[pix * 3 + 1] = cols[1];
        out[pix * 3 + 2] = cols[2];
        out[kB * kH * kW * 3 + pix] = improb;
    }
}

extern "C" void kernel_launch(void* const* d_in, const int* in_sizes, int n_in,
                              void* d_out, int out_size, void* d_ws, size_t ws_size,
                              hipStream_t stream) {
    const float* pts = (const float*)d_in[0];
    const int* faces = (const int*)d_in[1];
    const float* uvs = (const float*)d_in[2];
    const float* tex = (const float*)d_in[3];
    float* out = (float*)d_out;
    float4* ws4 = (float4*)d_ws;  // needs 98,304 B; ws_size >= 102,464 proven in R1
    prep<<<kB, 512, 0, stream>>>(pts, faces, uvs, ws4);
    render<<<kB * 256, 512, 0, stream>>>(ws4, tex, out);
}

// Round 9
// 18.444 us; speedup vs baseline: 1.1798x; 1.1798x over previous
//
#include <hip/hip_runtime.h>
#include <math.h>

constexpr int kB = 2, kP = 300, kF = 512, kH = 128, kW = 128, kTH = 512, kTW = 512;
constexpr float kDelta = 7000.0f;
constexpr float kCut = 0.0363f;    // skip p < ~1e-4 contributions (improb err <= ~1e-3)
constexpr float kThr2 = 0.012928f; // (kCut + 0.0774 pixel-center tile radius)^2
constexpr float kLogInside = -15.9423847f; // log1p(-(1-1e-7f)) = ln(2^-23)

// One fused kernel. Grid: 512 blocks = 2 batches x 256 tiles (8x8 px).
// Block: 512 threads = 8 waves. Compacted front-face k DEALT to slot
// (k&7)*64 + (k>>3): wave wv owns slots [wv*64,wv*64+64) = faces k===wv (mod 8).
// L_i(p) = A_i px + B_i py + C_i = signed distance to edge-line i (unit normal).
__global__ __launch_bounds__(512, 6) void render_all(const float* __restrict__ pts,
                                                     const int* __restrict__ faces,
                                                     const float* __restrict__ uvs,
                                                     const float* __restrict__ tex,
                                                     float* __restrict__ out) {
    __shared__ float4 sA[kF], sB[kF], sC[kF];   // 24 KB hot records
    __shared__ float2 s_vtx[kF * 3];            // 12 KB verts (xy)
    __shared__ ushort4 s_j3[kF];                // 4 KB vertex indices
    __shared__ float s_uv[kP * 2];              // 2.4 KB staged uvs (batch b)
    __shared__ float s_bz[512];                 // reduce arrays
    __shared__ int s_bi[512];
    __shared__ float s_lm[512];
    __shared__ float4 s_pxW[64];                // per-pixel bilinear weights * mk
    __shared__ int4 s_pxO[64];                  // per-pixel texel offsets
    __shared__ int s_wsum[8];

    int tile = (int)blockIdx.x;
    int b = tile >> 8;
    int rem = tile & 255;
    int ty = rem >> 4, tx = rem & 15;
    int tid = (int)threadIdx.x;
    int lane = tid & 63;
    int wv = tid >> 6;

    // ---------- setup: thread tid processes face tid for batch b ----------
    {
        int f = tid;
        int i0 = faces[f * 3 + 0], i1 = faces[f * 3 + 1], i2 = faces[f * 3 + 2];
        const float* pb = pts + b * kP * 3;
        float x0 = pb[i0 * 3], y0 = pb[i0 * 3 + 1], z0 = pb[i0 * 3 + 2];
        float x1 = pb[i1 * 3], y1 = pb[i1 * 3 + 1], z1 = pb[i1 * 3 + 2];
        float x2 = pb[i2 * 3], y2 = pb[i2 * 3 + 1], z2 = pb[i2 * 3 + 2];
        float area = (x1 - x0) * (y2 - y0) - (y1 - y0) * (x2 - x0);
        bool front = area > 1e-8f;

        // stage uvs coalesced (for the reduce-wave uv interpolation)
        const float* gu = uvs + b * (kP * 2);
        for (int i = tid; i < kP * 2; i += 512) s_uv[i] = gu[i];
        // prefill: empty slots never inside / never admitted, NaN-free
        sA[f] = make_float4(0.0f, 0.0f, -1e30f, 0.0f);
        sB[f] = make_float4(0.0f, -1e30f, 0.0f, 0.0f);
        sC[f] = make_float4(-1e30f, 0.0f, 0.0f, 0.0f);
        s_vtx[f * 3 + 0] = make_float2(1e15f, 1e15f);
        s_vtx[f * 3 + 1] = make_float2(1e15f, 1e15f);
        s_vtx[f * 3 + 2] = make_float2(1e15f, 1e15f);
        unsigned long long bal = __ballot(front);
        if (lane == 0) s_wsum[wv] = __popcll(bal);
        __syncthreads();  // wsum + prefill visible

        int base = 0;
#pragma unroll
        for (int w = 0; w < 8; ++w) base += (w < wv) ? s_wsum[w] : 0;
        int k = base + __popcll(bal & ((1ull << lane) - 1ull));  // compacted idx

        if (front) {
            int slot = ((k & 7) << 6) | (k >> 3);  // deal across waves
            float inv_a = 1.0f / area;
            float e0x = x2 - x1, e0y = y2 - y1;
            float e1x = x0 - x2, e1y = y0 - y2;
            float e2x = x1 - x0, e2y = y1 - y0;
            float l0 = fmaf(e0x, e0x, e0y * e0y);
            float l1 = fmaf(e1x, e1x, e1y * e1y);
            float l2 = fmaf(e2x, e2x, e2y * e2y);
            float s0 = rsqrtf(l0 + 1e-12f);
            float s1 = rsqrtf(l1 + 1e-12f);
            float s2 = rsqrtf(l2 + 1e-12f);
            float A0 = -e0y * s0, B0 = e0x * s0, C0 = (e0y * x1 - e0x * y1) * s0;
            float A1 = -e1y * s1, B1 = e1x * s1, C1 = (e1y * x2 - e1x * y2) * s1;
            float A2 = -e2y * s2, B2 = e2x * s2, C2 = (e2y * x0 - e2x * y0) * s2;
            float a0 = -e0y * inv_a, b0 = e0x * inv_a, c0 = (e0y * x1 - e0x * y1) * inv_a;
            float a1 = -e1y * inv_a, b1 = e1x * inv_a, c1 = (e1y * x2 - e1x * y2) * inv_a;
            float a2 = -e2y * inv_a, b2 = e2x * inv_a, c2 = (e2y * x0 - e2x * y0) * inv_a;
            sA[slot] = make_float4(A0, B0, C0, A1);
            sB[slot] = make_float4(B1, C1, A2, B2);
            sC[slot] = make_float4(C2,
                                   a0 * z0 + a1 * z1 + a2 * z2,
                                   b0 * z0 + b1 * z1 + b2 * z2,
                                   c0 * z0 + c1 * z1 + c2 * z2);
            s_vtx[slot * 3 + 0] = make_float2(x0, y0);
            s_vtx[slot * 3 + 1] = make_float2(x1, y1);
            s_vtx[slot * 3 + 2] = make_float2(x2, y2);
            s_j3[slot] = make_ushort4((unsigned short)i0, (unsigned short)i1,
                                      (unsigned short)i2, 0);
        }
    }
    __syncthreads();

    // ---------- render ----------
    int pyi = ty * 8 + (lane >> 3);
    int pxi = tx * 8 + (lane & 7);
    float px = ((float)pxi + 0.5f) * (2.0f / 128.0f) - 1.0f;
    float py = 1.0f - ((float)pyi + 0.5f) * (2.0f / 128.0f);

    // cull: lane l tests slot wv*64+l, exact dist-to-triangle at tile center
    float cx = (float)(tx * 8 + 4) * (2.0f / 128.0f) - 1.0f;
    float cy = 1.0f - (float)(ty * 8 + 4) * (2.0f / 128.0f);
    unsigned long long m;
    {
        int slt = (wv << 6) + lane;  // lane-contiguous -> conflict-light reads
        float4 a4 = sA[slt];
        float4 b4 = sB[slt];
        float4 c4 = sC[slt];
        float L0 = fmaf(a4.x, cx, fmaf(a4.y, cy, a4.z));
        float L1 = fmaf(a4.w, cx, fmaf(b4.x, cy, b4.y));
        float L2 = fmaf(b4.z, cx, fmaf(b4.w, cy, c4.x));
        float minc = fminf(fminf(L0, L1), L2);
        float2 v0 = s_vtx[slt * 3 + 0];
        float2 v1 = s_vtx[slt * 3 + 1];
        float2 v2 = s_vtx[slt * 3 + 2];
        float e0x = v2.x - v1.x, e0y = v2.y - v1.y;
        float e1x = v0.x - v2.x, e1y = v0.y - v2.y;
        float e2x = v1.x - v0.x, e2y = v1.y - v0.y;
        float p0x = cx - v0.x, p0y = cy - v0.y;
        float p1x = cx - v1.x, p1y = cy - v1.y;
        float p2x = cx - v2.x, p2y = cy - v2.y;
        float dot0 = fmaf(p1x, e0x, p1y * e0y), len0 = fmaf(e0x, e0x, e0y * e0y);
        float dot1 = fmaf(p2x, e1x, p2y * e1y), len1 = fmaf(e1x, e1x, e1y * e1y);
        float dot2 = fmaf(p0x, e2x, p0y * e2y), len2 = fmaf(e2x, e2x, e2y * e2y);
        float c0 = (dot0 >= 0.0f && dot0 <= len0) ? L0 * L0 : 1e30f;
        float c1 = (dot1 >= 0.0f && dot1 <= len1) ? L1 * L1 : 1e30f;
        float c2 = (dot2 >= 0.0f && dot2 <= len2) ? L2 * L2 : 1e30f;
        float dv0 = fmaf(p0x, p0x, p0y * p0y);
        float dv1 = fmaf(p1x, p1x, p1y * p1y);
        float dv2 = fmaf(p2x, p2x, p2y * p2y);
        float d2c = fminf(fminf(fminf(c0, c1), fminf(c2, dv0)), fminf(dv1, dv2));
        bool admit = (minc >= 0.0f) | (d2c <= kThr2);
        m = __ballot(admit);
    }

    float bestz = -1e9f;
    int besti = -1, icnt = 0;  // besti = compacted index k (global face order)
    float lm = 0.0f;

    // 1-deep software-pipelined mask loop (m is wave-uniform)
    int l = -1;
    float4 h0, h1, h2;
    if (m) {
        l = (int)__builtin_ctzll(m);
        m &= (m - 1);
        int fs = (wv << 6) + l;
        h0 = sA[fs]; h1 = sB[fs]; h2 = sC[fs];
    }
    while (l >= 0) {
        // prefetch next record while processing current
        int l2 = -1;
        float4 n0, n1, n2;
        if (m) {
            l2 = (int)__builtin_ctzll(m);
            m &= (m - 1);
            int fs2 = (wv << 6) + l2;
            n0 = sA[fs2]; n1 = sB[fs2]; n2 = sC[fs2];
        }
        int fs = (wv << 6) + l;
        int k = (l << 3) | wv;  // compacted face index, ascending in l
        float L0 = fmaf(h0.x, px, fmaf(h0.y, py, h0.z));
        float L1 = fmaf(h0.w, px, fmaf(h1.x, py, h1.y));
        float L2 = fmaf(h1.z, px, fmaf(h1.w, py, h2.x));
        float minL = fminf(fminf(L0, L1), L2);
        bool inside = minL >= 0.0f;
        float z = fmaf(h2.y, px, fmaf(h2.z, py, h2.w));
        if (inside && z > bestz) { bestz = z; besti = k; }
        icnt += inside ? 1 : 0;
        float db = fminf(fminf(fabsf(L0), fabsf(L1)), fabsf(L2));  // dist lower bound
        bool need = (!inside) & (db < kCut);
        if (__any(need)) {
            float2 v0 = s_vtx[fs * 3 + 0];
            float2 v1 = s_vtx[fs * 3 + 1];
            float2 v2 = s_vtx[fs * 3 + 2];
            float e0x = v2.x - v1.x, e0y = v2.y - v1.y;
            float e1x = v0.x - v2.x, e1y = v0.y - v2.y;
            float e2x = v1.x - v0.x, e2y = v1.y - v0.y;
            float p0x = px - v0.x, p0y = py - v0.y;
            float p1x = px - v1.x, p1y = py - v1.y;
            float p2x = px - v2.x, p2y = py - v2.y;
            float dot0 = fmaf(p1x, e0x, p1y * e0y), len0 = fmaf(e0x, e0x, e0y * e0y);
            float dot1 = fmaf(p2x, e1x, p2y * e1y), len1 = fmaf(e1x, e1x, e1y * e1y);
            float dot2 = fmaf(p0x, e2x, p0y * e2y), len2 = fmaf(e2x, e2x, e2y * e2y);
            float c0 = (dot0 >= 0.0f && dot0 <= len0) ? L0 * L0 : 1e30f;
            float c1 = (dot1 >= 0.0f && dot1 <= len1) ? L1 * L1 : 1e30f;
            float c2 = (dot2 >= 0.0f && dot2 <= len2) ? L2 * L2 : 1e30f;
            float dv0 = fmaf(p0x, p0x, p0y * p0y);
            float dv1 = fmaf(p1x, p1x, p1y * p1y);
            float dv2 = fmaf(p2x, p2x, p2y * p2y);
            float d2 = fminf(fminf(fminf(c0, c1), fminf(c2, dv0)), fminf(dv1, dv2));
            float p = __expf(-kDelta * d2);
            p = fminf(p, 1.0f - 1e-7f);
            float lp = __logf(1.0f - p);  // == log1p(-p) over admitted range
            lm += need ? lp : 0.0f;
        }
        l = l2; h0 = n0; h1 = n1; h2 = n2;
    }
    lm = fmaf((float)icnt, kLogInside, lm);

    s_bz[tid] = bestz;
    s_bi[tid] = besti;
    s_lm[tid] = lm;
    __syncthreads();

    // ---------- reduce + fragment prep (wave 0) ----------
    if (tid < 64) {
        float bz = s_bz[tid];
        int bi = s_bi[tid];
        float L = s_lm[tid];
#pragma unroll
        for (int w = 1; w < 8; ++w) {
            float z2 = s_bz[w * 64 + tid];
            int ii = s_bi[w * 64 + tid];
            L += s_lm[w * 64 + tid];
            // first-max: lowest compacted index (earliest original face) wins ties
            if (z2 > bz || (z2 == bz && ii >= 0 && (unsigned)ii < (unsigned)bi)) {
                bz = z2; bi = ii;
            }
        }
        float improb = 1.0f - expf(L);
        float u = 0.0f, v = 0.0f, mk = 0.0f;
        if (bi >= 0) {
            int slot = ((bi & 7) << 6) | (bi >> 3);
            float2 v0 = s_vtx[slot * 3 + 0];
            float2 v1 = s_vtx[slot * 3 + 1];
            float2 v2 = s_vtx[slot * 3 + 2];
            float area = (v1.x - v0.x) * (v2.y - v0.y) - (v1.y - v0.y) * (v2.x - v0.x);
            float inv_a = 1.0f / area;
            // exact reference formulation
            float w0 = ((v2.x - v1.x) * (py - v1.y) - (v2.y - v1.y) * (px - v1.x)) * inv_a;
            float w1 = ((v0.x - v2.x) * (py - v2.y) - (v0.y - v2.y) * (px - v2.x)) * inv_a;
            float w2 = ((v1.x - v0.x) * (py - v0.y) - (v1.y - v0.y) * (px - v0.x)) * inv_a;
            ushort4 j = s_j3[slot];
            u = w0 * s_uv[j.x * 2] + w1 * s_uv[j.y * 2] + w2 * s_uv[j.z * 2];
            v = w0 * s_uv[j.x * 2 + 1] + w1 * s_uv[j.y * 2 + 1] + w2 * s_uv[j.z * 2 + 1];
            mk = w0 + w1 + w2;
        }
        float uc = fminf(fmaxf(u, 0.0f), 1.0f);
        float vc = fminf(fmaxf(v, 0.0f), 1.0f);
        float fx = uc * (float)(kTW - 1);
        float fy = (1.0f - vc) * (float)(kTH - 1);
        int xi0 = (int)floorf(fx), yi0 = (int)floorf(fy);
        int xi1 = min(xi0 + 1, kTW - 1), yi1 = min(yi0 + 1, kTH - 1);
        float wx = fx - (float)xi0, wy = fy - (float)yi0;
        // fold mk into the bilinear weights
        float w00 = (1.0f - wx) * (1.0f - wy) * mk;
        float w01 = wx * (1.0f - wy) * mk;
        float w10 = (1.0f - wx) * wy * mk;
        float w11 = wx * wy * mk;
        s_pxW[tid] = make_float4(w00, w01, w10, w11);
        s_pxO[tid] = make_int4(yi0 * kTW + xi0, yi0 * kTW + xi1,
                               yi1 * kTW + xi0, yi1 * kTW + xi1);
        out[kB * kH * kW * 3 + (b * kH + pyi) * kW + pxi] = improb;
    }
    __syncthreads();

    // ---------- fragment shader: 192 threads = 64 px x 3 channels ----------
    if (tid < 192) {
        int pix = tid & 63;
        int c = tid >> 6;
        float4 w = s_pxW[pix];
        int4 o = s_pxO[pix];
        const float* tc = tex + ((size_t)b * 3 + c) * kTH * kTW;
        float col = tc[o.x] * w.x + tc[o.y] * w.y + tc[o.z] * w.z + tc[o.w] * w.w;
        int qy = ty * 8 + (pix >> 3);
        int qx = tx * 8 + (pix & 7);
        out[((b * kH + qy) * kW + qx) * 3 + c] = col;
    }
}

extern "C" void kernel_launch(void* const* d_in, const int* in_sizes, int n_in,
                              void* d_out, int out_size, void* d_ws, size_t ws_size,
                              hipStream_t stream) {
    const float* pts = (const float*)d_in[0];
    const int* faces = (const int*)d_in[1];
    const float* uvs = (const float*)d_in[2];
    const float* tex = (const float*)d_in[3];
    float* out = (float*)d_out;
    render_all<<<kB * 256, 512, 0, stream>>>(pts, faces, uvs, tex, out);
}